// Round 2
// baseline (785.549 us; speedup 1.0000x reference)
//
#include <hip/hip_runtime.h>

// Entmax-1.5 loss, n=4096 rows x d=32000 fp32 logits -> scalar mean loss.
// Root-finding formulation (no sort): tau solves sum clip(x/2 - tau, 0)^2 = 1.
// Single streaming HBM pass; candidates (v > subsample_max - 2, provably a
// superset of the support) appended to LDS; wave 0 Newton-iterates + exact
// quadratic solve (== reference formula) over ~170 survivors.

#define D          32000
#define NF4        8000      // D/4
#define BLK        1024
#define CAP        8192      // LDS candidate buffer; ~2000 expected
#define CAP2       1024      // compacted (y > c-1) buffer; ~170 expected
#define NEWTON_IT  12

__global__ __launch_bounds__(BLK)
void entmax15_loss_rows(const float* __restrict__ x,
                        const int* __restrict__ tgt,
                        float* __restrict__ out,
                        float inv_n) {
    __shared__ float s_buf[CAP];
    __shared__ float s_buf2[CAP2];
    __shared__ float s_red[16];
    __shared__ float s_m0, s_max;
    __shared__ int   s_cnt, s_cnt2;

    const int tid  = threadIdx.x;
    const int lane = tid & 63;
    const int wave = tid >> 6;
    const int r    = blockIdx.x;
    const float* row  = x + (size_t)r * D;
    const float4* row4 = (const float4*)row;

    if (tid == 0) { s_cnt = 0; s_cnt2 = 0; }

    // ---- chunk 0: subsample max over first 4096 elements ----
    float4 c0 = row4[tid];
    float m = fmaxf(fmaxf(c0.x, c0.y), fmaxf(c0.z, c0.w));
    float mm = m;
#pragma unroll
    for (int off = 32; off > 0; off >>= 1) mm = fmaxf(mm, __shfl_xor(mm, off));
    if (lane == 0) s_red[wave] = mm;
    __syncthreads();
    if (tid < 64) {
        float t = (lane < 16) ? s_red[lane] : -1e30f;
#pragma unroll
        for (int off = 8; off > 0; off >>= 1) t = fmaxf(t, __shfl_xor(t, off));
        if (lane == 0) s_m0 = t;
    }
    __syncthreads();

    const float thr = s_m0 - 2.0f;   // m0 <= truemax  =>  thr <= truemax - 2 (safe)

    // ballot-aggregated LDS append (1 atomic per wave per call site)
    auto push = [&](float vv) {
        bool pr = vv > thr;
        unsigned long long mask = __ballot(pr);
        if (mask) {
            int nb = __popcll(mask);
            int leader = __ffsll((long long)mask) - 1;
            int base = 0;
            if (lane == leader) base = atomicAdd(&s_cnt, nb);
            base = __shfl(base, leader);
            if (pr) {
                int idx = base + __popcll(mask & ((1ull << lane) - 1ull));
                if (idx < CAP) s_buf[idx] = 0.5f * vv;
            }
        }
    };

    push(c0.x); push(c0.y); push(c0.z); push(c0.w);

    // ---- chunks 1..6 + remainder: stream, track true max, append ----
#pragma unroll
    for (int i = 1; i < 7; ++i) {
        float4 t = row4[tid + i * 1024];
        m = fmaxf(m, fmaxf(fmaxf(t.x, t.y), fmaxf(t.z, t.w)));
        push(t.x); push(t.y); push(t.z); push(t.w);
    }
    {
        bool act = tid < (NF4 - 7 * 1024);   // 832 remaining float4s
        float4 t = act ? row4[tid + 7 * 1024]
                       : make_float4(-1e30f, -1e30f, -1e30f, -1e30f);
        m = fmaxf(m, fmaxf(fmaxf(t.x, t.y), fmaxf(t.z, t.w)));
        push(t.x); push(t.y); push(t.z); push(t.w);
    }

    // ---- true block max ----
#pragma unroll
    for (int off = 32; off > 0; off >>= 1) m = fmaxf(m, __shfl_xor(m, off));
    if (lane == 0) s_red[wave] = m;
    __syncthreads();
    if (tid < 64) {
        float t = (lane < 16) ? s_red[lane] : -1e30f;
#pragma unroll
        for (int off = 8; off > 0; off >>= 1) t = fmaxf(t, __shfl_xor(t, off));
        if (lane == 0) s_max = t;
    }
    __syncthreads();

    if (tid >= 64) return;            // wave 0 finishes the row alone

    const float c    = 0.5f * s_max;
    const float Tcap = c - 0.0055f;   // tau <= c - 1/sqrt(d) = c - 0.00559
    int  cnt = s_cnt;
    bool ovf = cnt > CAP;             // impossible for this data; safe fallback
    if (ovf) cnt = CAP;

    // ---- compact to provable support superset: y > c - 1 ----
    const float* cb = s_buf;
    int cn = cnt;
    if (!ovf) {
        const float lo = c - 1.0f;
        for (int j = lane; j < cnt; j += 64) {
            float y = s_buf[j];
            if (y > lo) {
                int p = atomicAdd(&s_cnt2, 1);
                if (p < CAP2) s_buf2[p] = y;
            }
        }
        int c2 = s_cnt2;
        if (c2 <= CAP2) { cb = s_buf2; cn = c2; }
    }

    // ---- Newton from below + final exact quadratic solve ----
    float T = c - 1.0f;
    for (int it = 0; it <= NEWTON_IT; ++it) {
        float k = 0.f, B = 0.f, A = 0.f;
        if (!ovf) {
            for (int j = lane; j < cn; j += 64) {
                float y = cb[j];
                if (y > T) { k += 1.f; B += y; A = fmaf(y, y, A); }
            }
        } else {
            for (int j = lane; j < D; j += 64) {
                float y = 0.5f * row[j];
                if (y > T) { k += 1.f; B += y; A = fmaf(y, y, A); }
            }
        }
#pragma unroll
        for (int off = 32; off > 0; off >>= 1) {
            k += __shfl_xor(k, off);
            B += __shfl_xor(B, off);
            A += __shfl_xor(A, off);
        }
        if (it < NEWTON_IT) {
            // f(T) = k*T^2 - 2*B*T + A ; f'(T) = -2*(B - k*T)
            float f  = fmaf(fmaf(k, T, -2.f * B), T, A);
            float s1 = B - k * T;
            T = fminf(T + 0.5f * (f - 1.f) / s1, Tcap);
        } else {
            // exact solve over stabilized support (reference formula)
            float mean  = B / k;
            float delta = fmaxf(fmaf(mean, mean, -(A - 1.f) / k), 0.f);
            T = fminf(mean - sqrtf(delta), Tcap);
        }
    }

    // ---- final stats: S15 = sum u^3, Spx = sum u^2 * x  (u = y - T > 0) ----
    float S15 = 0.f, Spx = 0.f;
    if (!ovf) {
        for (int j = lane; j < cn; j += 64) {
            float y = cb[j];
            float u = y - T;
            if (u > 0.f) { float p = u * u; S15 = fmaf(p, u, S15); Spx = fmaf(p, 2.f * y, Spx); }
        }
    } else {
        for (int j = lane; j < D; j += 64) {
            float y = 0.5f * row[j];
            float u = y - T;
            if (u > 0.f) { float p = u * u; S15 = fmaf(p, u, S15); Spx = fmaf(p, 2.f * y, Spx); }
        }
    }
#pragma unroll
    for (int off = 32; off > 0; off >>= 1) {
        S15 += __shfl_xor(S15, off);
        Spx += __shfl_xor(Spx, off);
    }

    if (lane == 0) {
        float xt   = row[tgt[r]];
        float loss = (1.f - S15) * (4.f / 3.f) + Spx - xt;
        atomicAdd(out, loss * inv_n);
    }
}

extern "C" void kernel_launch(void* const* d_in, const int* in_sizes, int n_in,
                              void* d_out, int out_size, void* d_ws, size_t ws_size,
                              hipStream_t stream) {
    const float* xin = (const float*)d_in[0];
    const int*   tgt = (const int*)d_in[1];
    float*       out = (float*)d_out;
    const int n = in_sizes[0] / D;   // 4096 rows

    hipMemsetAsync(out, 0, sizeof(float), stream);
    entmax15_loss_rows<<<n, BLK, 0, stream>>>(xin, tgt, out, 1.0f / (float)n);
}